// Round 1
// baseline (327.054 us; speedup 1.0000x reference)
//
#include <hip/hip_runtime.h>
#include <math.h>

// ---------------- problem constants ----------------
#define B_TOT 8192
#define KE 400      // 16 nodes * 25 t
#define KR 300      // 12 nodes * 25 t
#define KRP 304     // padded to multiple of KC
#define KC 16       // k-chunk

// ---------------- workspace layout (float offsets) ----------------
#define OFF_WEFF0E 0
#define OFF_WEFF1E 1600
#define OFF_WEFF0R 3200
#define OFF_WEFF1R 4800
#define OFF_CVE    6400
#define OFF_CVR    6464
#define OFF_AE     6528                     // A_ecc [400][256]
#define OFF_AR     (OFF_AE + KE * 256)      // A_err [304][256] (rows 300..303 zero)
#define OFF_BE     (OFF_AR + KRP * 256)     // bias_ecc [256]
#define OFF_BR     (OFF_BE + 256)           // bias_err [256]
#define OFF_GE     (OFF_BR + 256)           // ecc_g [8192][256]
#define OFF_GR     (OFF_GE + B_TOT * 256)   // err_g [8192][256]

__device__ __forceinline__ float sigmoidf_(float x) { return 1.f / (1.f + __expf(-x)); }
__device__ __forceinline__ float tanhf_(float x) { float e = __expf(2.f * x); return (e - 1.f) / (e + 1.f); }

// =====================================================================
// Kernel 1: fold Conv1d into W0/W1 -> Weff [25][64] per (branch, order),
// plus cvec[64] = b + sum_ct bt[c]*(W0-W1)[ct]  (ring row-sum of L_hat = -1)
// grid = 6 blocks x 256 threads
// =====================================================================
__global__ void fold_temporal(
    const float* __restrict__ wt_ecc, const float* __restrict__ bt_ecc,
    const float* __restrict__ wt_err, const float* __restrict__ bt_err,
    const float* __restrict__ W0_ecc, const float* __restrict__ W1_ecc, const float* __restrict__ b_ecc,
    const float* __restrict__ W0_err, const float* __restrict__ W1_err, const float* __restrict__ b_err,
    float* __restrict__ ws)
{
    const int m = blockIdx.x;
    const int tid = threadIdx.x;
    if (m < 4) {
        const bool is_err = (m >= 2);
        const float* wt = is_err ? wt_err : wt_ecc;
        const float* W = (m & 1) ? (is_err ? W1_err : W1_ecc) : (is_err ? W0_err : W0_ecc);
        float* out = ws + m * 1600;
        for (int idx = tid; idx < 1600; idx += 256) {
            const int tin = idx >> 6;   // 0..24
            const int g = idx & 63;
            const int t0 = tin > 0 ? tin - 1 : 0;
            const int t1 = tin < 24 ? tin + 1 : 24;
            float s = 0.f;
            for (int c = 0; c < 32; ++c) {
                for (int t = t0; t <= t1; ++t) {
                    const int k = tin - t + 1;           // 0..2
                    s = fmaf(wt[c * 3 + k], W[(c * 25 + t) * 64 + g], s);
                }
            }
            out[idx] = s;
        }
    } else {
        const bool is_err = (m == 5);
        const float* bt = is_err ? bt_err : bt_ecc;
        const float* W0 = is_err ? W0_err : W0_ecc;
        const float* W1 = is_err ? W1_err : W1_ecc;
        const float* bb = is_err ? b_err : b_ecc;
        float* out = ws + (is_err ? OFF_CVR : OFF_CVE);
        if (tid < 64) {
            const int g = tid;
            float s = bb[g];
            for (int c = 0; c < 32; ++c) {
                const float btc = bt[c];
                for (int t = 0; t < 25; ++t) {
                    const int ct = (c * 25 + t) * 64 + g;
                    s = fmaf(btc, W0[ct] - W1[ct], s);
                }
            }
            out[g] = s;
        }
    }
}

// =====================================================================
// Kernel 2: fold Weff + ring stencil + Wp -> A_ecc[400][256], A_err[304][256],
// bias_ecc[256], bias_err[256].
// grid = 400 + 304 + 2 = 706 blocks x 256 threads (thread = output col h)
// =====================================================================
__global__ void fold_graph(
    const float* __restrict__ Wp_ecc, const float* __restrict__ bp_ecc,
    const float* __restrict__ Wp_err, const float* __restrict__ bp_err,
    float* __restrict__ ws)
{
    const int blk = blockIdx.x;
    const int h = threadIdx.x;
    if (blk < KE) {
        const int k = blk, v = k / 25, tin = k % 25;
        const int vp = (v + 1) & 15, vm = (v + 15) & 15;
        const float* w0 = ws + OFF_WEFF0E + tin * 64;
        const float* w1 = ws + OFF_WEFF1E + tin * 64;
        float s = 0.f;
        #pragma unroll 4
        for (int g = 0; g < 64; ++g) {
            s = fmaf(w0[g], Wp_ecc[(v * 64 + g) * 256 + h], s);
            s = fmaf(-0.5f * w1[g], Wp_ecc[(vp * 64 + g) * 256 + h] + Wp_ecc[(vm * 64 + g) * 256 + h], s);
        }
        ws[OFF_AE + (size_t)k * 256 + h] = s;
    } else if (blk < KE + KRP) {
        const int k = blk - KE;
        if (k >= KR) { ws[OFF_AR + (size_t)k * 256 + h] = 0.f; return; }
        const int v = k / 25, tin = k % 25;
        const int vp = (v + 1) % 12, vm = (v + 11) % 12;
        const float* w0 = ws + OFF_WEFF0R + tin * 64;
        const float* w1 = ws + OFF_WEFF1R + tin * 64;
        float s = 0.f;
        #pragma unroll 4
        for (int g = 0; g < 64; ++g) {
            s = fmaf(w0[g], Wp_err[(v * 64 + g) * 256 + h], s);
            s = fmaf(-0.5f * w1[g], Wp_err[(vp * 64 + g) * 256 + h] + Wp_err[(vm * 64 + g) * 256 + h], s);
        }
        ws[OFF_AR + (size_t)k * 256 + h] = s;
    } else if (blk == KE + KRP) {
        const float* cv = ws + OFF_CVE;
        float s = bp_ecc[h];
        for (int v = 0; v < 16; ++v)
            for (int g = 0; g < 64; ++g)
                s = fmaf(cv[g], Wp_ecc[(v * 64 + g) * 256 + h], s);
        ws[OFF_BE + h] = s;
    } else {
        const float* cv = ws + OFF_CVR;
        float s = bp_err[h];
        for (int v = 0; v < 12; ++v)
            for (int g = 0; g < 64; ++g)
                s = fmaf(cv[g], Wp_err[(v * 64 + g) * 256 + h], s);
        ws[OFF_BR + h] = s;
    }
}

// =====================================================================
// Kernel 3: GEMM  G = X @ A + bias  for both branches.
// grid = 512 blocks: bid = (rowTile<<2) | (colHalf<<1) | branch
// tile 64 rows x 128 cols, 256 threads, 4x8 micro-tile per thread.
// =====================================================================
__global__ __launch_bounds__(256) void gemm_g(
    const float* __restrict__ xecc, const float* __restrict__ xerr,
    float* __restrict__ ws)
{
    const int bid = blockIdx.x;
    const int branch = bid & 1;
    const int colh = (bid >> 1) & 1;
    const int rowt = bid >> 2;

    const float* X = branch ? xerr : xecc;
    const float* A = ws + (branch ? OFF_AR : OFF_AE);
    const float* bias = ws + (branch ? OFF_BR : OFF_BE);
    float* G = ws + (branch ? OFF_GR : OFF_GE);
    const int K = branch ? KR : KE;     // true K (for x bounds)
    const int KP = branch ? KRP : KE;   // padded loop bound
    const int ldx = K;

    const int b0 = rowt * 64;
    const int n0 = colh * 128;

    __shared__ float sx[KC][64];    // 4 KB
    __shared__ float swt[KC][128];  // 8 KB

    const int tid = threadIdx.x;
    const int cg = tid & 15;        // 16 col groups * 8 cols
    const int rg = tid >> 4;        // 16 row groups * 4 rows
    const int r0 = rg * 4;
    const int c0l = cg * 8;

    float acc[4][8];
    {
        const float* bsrc = bias + n0 + c0l;
        const float4 bv0 = ((const float4*)bsrc)[0];
        const float4 bv1 = ((const float4*)bsrc)[1];
        const float bi[8] = {bv0.x, bv0.y, bv0.z, bv0.w, bv1.x, bv1.y, bv1.z, bv1.w};
        #pragma unroll
        for (int i = 0; i < 4; ++i)
            #pragma unroll
            for (int j = 0; j < 8; ++j)
                acc[i][j] = bi[j];
    }

    for (int kc = 0; kc < KP; kc += KC) {
        // stage x: 64 rows x 16 k, thread -> (row, 4 k)
        {
            const int row = tid >> 2;
            const int kq = (tid & 3) * 4;
            const int kg = kc + kq;
            float4 xv = make_float4(0.f, 0.f, 0.f, 0.f);
            if (kg < K) xv = *(const float4*)(X + (size_t)(b0 + row) * ldx + kg);
            sx[kq + 0][row] = xv.x;
            sx[kq + 1][row] = xv.y;
            sx[kq + 2][row] = xv.z;
            sx[kq + 3][row] = xv.w;
        }
        // stage A: 16 k x 128 cols, thread -> (k, 8 cols)
        {
            const int k = tid >> 4;
            const int c = (tid & 15) * 8;
            const float* src = A + (size_t)(kc + k) * 256 + n0 + c;
            const float4 a0 = ((const float4*)src)[0];
            const float4 a1 = ((const float4*)src)[1];
            ((float4*)&swt[k][c])[0] = a0;
            ((float4*)&swt[k][c])[1] = a1;
        }
        __syncthreads();
        #pragma unroll
        for (int kk = 0; kk < KC; ++kk) {
            const float4 xv = *(const float4*)&sx[kk][r0];
            const float4 w0 = *(const float4*)&swt[kk][c0l];
            const float4 w1 = *(const float4*)&swt[kk][c0l + 4];
            const float xa[4] = {xv.x, xv.y, xv.z, xv.w};
            const float wb[8] = {w0.x, w0.y, w0.z, w0.w, w1.x, w1.y, w1.z, w1.w};
            #pragma unroll
            for (int i = 0; i < 4; ++i)
                #pragma unroll
                for (int j = 0; j < 8; ++j)
                    acc[i][j] = fmaf(xa[i], wb[j], acc[i][j]);
        }
        __syncthreads();
    }

    #pragma unroll
    for (int i = 0; i < 4; ++i) {
        float* dst = G + (size_t)(b0 + r0 + i) * 256 + n0 + c0l;
        ((float4*)dst)[0] = make_float4(acc[i][0], acc[i][1], acc[i][2], acc[i][3]);
        ((float4*)dst)[1] = make_float4(acc[i][4], acc[i][5], acc[i][6], acc[i][7]);
    }
}

// =====================================================================
// Kernel 4: per-row epilogue. One wave per row, 4 waves/block, grid 2048.
// attn = sigmoid(tanh(e+r)@Wa + ba); fused = attn*e+(1-attn)*r;
// ehr_p = relu(ehr@We+be); out = sigmoid(relu([fused,ehr_p])@Wf2 + bf2)
// =====================================================================
__global__ __launch_bounds__(256) void epilogue(
    const float* __restrict__ ehr, const float* __restrict__ ws,
    const float* __restrict__ Wa, const float* __restrict__ ba,
    const float* __restrict__ We, const float* __restrict__ be,
    const float* __restrict__ Wf2, const float* __restrict__ bf2,
    float* __restrict__ out)
{
    const int wid = threadIdx.x >> 6;
    const int lane = threadIdx.x & 63;
    const int row = blockIdx.x * 4 + wid;

    const float* ge = ws + OFF_GE + (size_t)row * 256;
    const float* gr = ws + OFF_GR + (size_t)row * 256;

    const float4 ev = *(const float4*)(ge + lane * 4);
    const float4 rv = *(const float4*)(gr + lane * 4);
    const float4 wav = *(const float4*)(Wa + lane * 4);

    float pa = tanhf_(ev.x + rv.x) * wav.x
             + tanhf_(ev.y + rv.y) * wav.y
             + tanhf_(ev.z + rv.z) * wav.z
             + tanhf_(ev.w + rv.w) * wav.w;
    #pragma unroll
    for (int m = 1; m < 64; m <<= 1) pa += __shfl_xor(pa, m, 64);
    const float at = sigmoidf_(pa + ba[0]);
    const float omat = 1.f - at;

    const float4 wfv = *(const float4*)(Wf2 + lane * 4);
    float po = fmaxf(at * ev.x + omat * rv.x, 0.f) * wfv.x
             + fmaxf(at * ev.y + omat * rv.y, 0.f) * wfv.y
             + fmaxf(at * ev.z + omat * rv.z, 0.f) * wfv.z
             + fmaxf(at * ev.w + omat * rv.w, 0.f) * wfv.w;

    // ehr branch: lane owns output feature e = lane
    const float x0 = ehr[(size_t)row * 64 + lane];
    float ep = be[lane];
    for (int d = 0; d < 64; ++d) {
        const float xd = __shfl(x0, d, 64);
        ep = fmaf(xd, We[d * 64 + lane], ep);
    }
    po += fmaxf(ep, 0.f) * Wf2[256 + lane];

    #pragma unroll
    for (int m = 1; m < 64; m <<= 1) po += __shfl_xor(po, m, 64);
    if (lane == 0) out[row] = sigmoidf_(po + bf2[0]);
}

// =====================================================================
extern "C" void kernel_launch(void* const* d_in, const int* in_sizes, int n_in,
                              void* d_out, int out_size, void* d_ws, size_t ws_size,
                              hipStream_t stream)
{
    (void)in_sizes; (void)n_in; (void)out_size; (void)ws_size;
    const float* ecc    = (const float*)d_in[0];
    const float* err    = (const float*)d_in[1];
    const float* ehr    = (const float*)d_in[2];
    const float* wt_ecc = (const float*)d_in[3];
    const float* bt_ecc = (const float*)d_in[4];
    const float* wt_err = (const float*)d_in[5];
    const float* bt_err = (const float*)d_in[6];
    const float* W0_ecc = (const float*)d_in[7];
    const float* W1_ecc = (const float*)d_in[8];
    const float* b_ecc  = (const float*)d_in[9];
    const float* W0_err = (const float*)d_in[10];
    const float* W1_err = (const float*)d_in[11];
    const float* b_err  = (const float*)d_in[12];
    const float* Wp_ecc = (const float*)d_in[13];
    const float* bp_ecc = (const float*)d_in[14];
    const float* Wp_err = (const float*)d_in[15];
    const float* bp_err = (const float*)d_in[16];
    const float* Wa     = (const float*)d_in[17];
    const float* ba     = (const float*)d_in[18];
    const float* We     = (const float*)d_in[19];
    const float* be     = (const float*)d_in[20];
    const float* Wf2    = (const float*)d_in[21];
    const float* bf2    = (const float*)d_in[22];
    float* ws  = (float*)d_ws;
    float* out = (float*)d_out;

    fold_temporal<<<dim3(6), dim3(256), 0, stream>>>(
        wt_ecc, bt_ecc, wt_err, bt_err, W0_ecc, W1_ecc, b_ecc, W0_err, W1_err, b_err, ws);
    fold_graph<<<dim3(KE + KRP + 2), dim3(256), 0, stream>>>(
        Wp_ecc, bp_ecc, Wp_err, bp_err, ws);
    gemm_g<<<dim3((B_TOT / 64) * 4), dim3(256), 0, stream>>>(ecc, err, ws);
    epilogue<<<dim3(B_TOT / 4), dim3(256), 0, stream>>>(
        ehr, ws, Wa, ba, We, be, Wf2, bf2, out);
}

// Round 2
// 202.167 us; speedup vs baseline: 1.6177x; 1.6177x over previous
//
#include <hip/hip_runtime.h>
#include <math.h>

// ---------------- problem constants ----------------
#define B_TOT 8192
#define KE 400      // 16 nodes * 25 t
#define KR 300      // 12 nodes * 25 t
#define KRP 304     // padded to multiple of KC
#define KC 16       // k-chunk

// ---------------- workspace layout (float offsets) ----------------
#define OFF_WEFF0E 0
#define OFF_WEFF1E 1600
#define OFF_WEFF0R 3200
#define OFF_WEFF1R 4800
#define OFF_CVE    6400
#define OFF_CVR    6464
#define OFF_AE     6528                     // A_ecc [400][256]
#define OFF_AR     (OFF_AE + KE * 256)      // A_err [304][256] (rows 300..303 zero)
#define OFF_BE     (OFF_AR + KRP * 256)     // bias_ecc [256]
#define OFF_BR     (OFF_BE + 256)           // bias_err [256]
#define OFF_GE     (OFF_BR + 256)           // ecc_g [8192][256]
#define OFF_GR     (OFF_GE + B_TOT * 256)   // err_g [8192][256]

__device__ __forceinline__ float sigmoidf_(float x) { return 1.f / (1.f + __expf(-x)); }
__device__ __forceinline__ float tanhf_(float x) { float e = __expf(2.f * x); return (e - 1.f) / (e + 1.f); }

// =====================================================================
// Kernel 1: fold Conv1d into W0/W1 -> Weff [25][64] per (branch, order),
// plus cvec[64] = b + sum_ct bt[c]*(W0-W1)[ct]  (ring row-sum of L_hat = -1)
// R1: parallelized — one block per (m, tin) output row, c-loop split 4-way
// across thread-groups, LDS reduce. 102 blocks x 256 threads.
// =====================================================================
__global__ __launch_bounds__(256) void fold_temporal(
    const float* __restrict__ wt_ecc, const float* __restrict__ bt_ecc,
    const float* __restrict__ wt_err, const float* __restrict__ bt_err,
    const float* __restrict__ W0_ecc, const float* __restrict__ W1_ecc, const float* __restrict__ b_ecc,
    const float* __restrict__ W0_err, const float* __restrict__ W1_err, const float* __restrict__ b_err,
    float* __restrict__ ws)
{
    const int blk = blockIdx.x;
    const int tid = threadIdx.x;
    const int cq = tid >> 6;    // 0..3  (c-chunk of 8)
    const int g  = tid & 63;

    __shared__ float red[4][64];

    if (blk < 100) {
        const int m = blk / 25;       // 0: W0_ecc, 1: W1_ecc, 2: W0_err, 3: W1_err
        const int tin = blk % 25;
        const bool is_err = (m >= 2);
        const float* wt = is_err ? wt_err : wt_ecc;
        const float* W = (m & 1) ? (is_err ? W1_err : W1_ecc) : (is_err ? W0_err : W0_ecc);
        const int t0 = tin > 0 ? tin - 1 : 0;
        const int t1 = tin < 24 ? tin + 1 : 24;
        float s = 0.f;
        #pragma unroll
        for (int c8 = 0; c8 < 8; ++c8) {
            const int c = cq * 8 + c8;
            for (int t = t0; t <= t1; ++t) {
                const int k = tin - t + 1;           // 0..2
                s = fmaf(wt[c * 3 + k], W[(c * 25 + t) * 64 + g], s);
            }
        }
        red[cq][g] = s;
        __syncthreads();
        if (tid < 64)
            ws[m * 1600 + tin * 64 + g] = red[0][g] + red[1][g] + red[2][g] + red[3][g];
    } else {
        const bool is_err = (blk == 101);
        const float* bt = is_err ? bt_err : bt_ecc;
        const float* W0 = is_err ? W0_err : W0_ecc;
        const float* W1 = is_err ? W1_err : W1_ecc;
        const float* bb = is_err ? b_err : b_ecc;
        float s = 0.f;
        #pragma unroll
        for (int c8 = 0; c8 < 8; ++c8) {
            const int c = cq * 8 + c8;
            const float btc = bt[c];
            #pragma unroll
            for (int t = 0; t < 25; ++t) {
                const int ct = (c * 25 + t) * 64 + g;
                s = fmaf(btc, W0[ct] - W1[ct], s);
            }
        }
        red[cq][g] = s;
        __syncthreads();
        if (tid < 64)
            ws[(is_err ? OFF_CVR : OFF_CVE) + g] =
                bb[g] + red[0][g] + red[1][g] + red[2][g] + red[3][g];
    }
}

// =====================================================================
// Kernel 2: fold Weff + ring stencil + Wp -> A_ecc[400][256], A_err[304][256],
// bias_ecc[256], bias_err[256].
// grid = 400 + 304 + 2 = 706 blocks x 256 threads (thread = output col h)
// =====================================================================
__global__ void fold_graph(
    const float* __restrict__ Wp_ecc, const float* __restrict__ bp_ecc,
    const float* __restrict__ Wp_err, const float* __restrict__ bp_err,
    float* __restrict__ ws)
{
    const int blk = blockIdx.x;
    const int h = threadIdx.x;
    if (blk < KE) {
        const int k = blk, v = k / 25, tin = k % 25;
        const int vp = (v + 1) & 15, vm = (v + 15) & 15;
        const float* w0 = ws + OFF_WEFF0E + tin * 64;
        const float* w1 = ws + OFF_WEFF1E + tin * 64;
        float s = 0.f;
        #pragma unroll 4
        for (int g = 0; g < 64; ++g) {
            s = fmaf(w0[g], Wp_ecc[(v * 64 + g) * 256 + h], s);
            s = fmaf(-0.5f * w1[g], Wp_ecc[(vp * 64 + g) * 256 + h] + Wp_ecc[(vm * 64 + g) * 256 + h], s);
        }
        ws[OFF_AE + (size_t)k * 256 + h] = s;
    } else if (blk < KE + KRP) {
        const int k = blk - KE;
        if (k >= KR) { ws[OFF_AR + (size_t)k * 256 + h] = 0.f; return; }
        const int v = k / 25, tin = k % 25;
        const int vp = (v + 1) % 12, vm = (v + 11) % 12;
        const float* w0 = ws + OFF_WEFF0R + tin * 64;
        const float* w1 = ws + OFF_WEFF1R + tin * 64;
        float s = 0.f;
        #pragma unroll 4
        for (int g = 0; g < 64; ++g) {
            s = fmaf(w0[g], Wp_err[(v * 64 + g) * 256 + h], s);
            s = fmaf(-0.5f * w1[g], Wp_err[(vp * 64 + g) * 256 + h] + Wp_err[(vm * 64 + g) * 256 + h], s);
        }
        ws[OFF_AR + (size_t)k * 256 + h] = s;
    } else if (blk == KE + KRP) {
        const float* cv = ws + OFF_CVE;
        float s = bp_ecc[h];
        for (int v = 0; v < 16; ++v)
            for (int g = 0; g < 64; ++g)
                s = fmaf(cv[g], Wp_ecc[(v * 64 + g) * 256 + h], s);
        ws[OFF_BE + h] = s;
    } else {
        const float* cv = ws + OFF_CVR;
        float s = bp_err[h];
        for (int v = 0; v < 12; ++v)
            for (int g = 0; g < 64; ++g)
                s = fmaf(cv[g], Wp_err[(v * 64 + g) * 256 + h], s);
        ws[OFF_BR + h] = s;
    }
}

// =====================================================================
// Kernel 3: GEMM  G = X @ A + bias  for both branches.
// grid = 512 blocks: bid = (rowTile<<2) | (colHalf<<1) | branch
// tile 64 rows x 128 cols, 256 threads, 4x8 micro-tile per thread.
// =====================================================================
__global__ __launch_bounds__(256) void gemm_g(
    const float* __restrict__ xecc, const float* __restrict__ xerr,
    float* __restrict__ ws)
{
    const int bid = blockIdx.x;
    const int branch = bid & 1;
    const int colh = (bid >> 1) & 1;
    const int rowt = bid >> 2;

    const float* X = branch ? xerr : xecc;
    const float* A = ws + (branch ? OFF_AR : OFF_AE);
    const float* bias = ws + (branch ? OFF_BR : OFF_BE);
    float* G = ws + (branch ? OFF_GR : OFF_GE);
    const int K = branch ? KR : KE;     // true K (for x bounds)
    const int KP = branch ? KRP : KE;   // padded loop bound
    const int ldx = K;

    const int b0 = rowt * 64;
    const int n0 = colh * 128;

    __shared__ float sx[KC][64];    // 4 KB
    __shared__ float swt[KC][128];  // 8 KB

    const int tid = threadIdx.x;
    const int cg = tid & 15;        // 16 col groups * 8 cols
    const int rg = tid >> 4;        // 16 row groups * 4 rows
    const int r0 = rg * 4;
    const int c0l = cg * 8;

    float acc[4][8];
    {
        const float* bsrc = bias + n0 + c0l;
        const float4 bv0 = ((const float4*)bsrc)[0];
        const float4 bv1 = ((const float4*)bsrc)[1];
        const float bi[8] = {bv0.x, bv0.y, bv0.z, bv0.w, bv1.x, bv1.y, bv1.z, bv1.w};
        #pragma unroll
        for (int i = 0; i < 4; ++i)
            #pragma unroll
            for (int j = 0; j < 8; ++j)
                acc[i][j] = bi[j];
    }

    for (int kc = 0; kc < KP; kc += KC) {
        // stage x: 64 rows x 16 k, thread -> (row, 4 k)
        {
            const int row = tid >> 2;
            const int kq = (tid & 3) * 4;
            const int kg = kc + kq;
            float4 xv = make_float4(0.f, 0.f, 0.f, 0.f);
            if (kg < K) xv = *(const float4*)(X + (size_t)(b0 + row) * ldx + kg);
            sx[kq + 0][row] = xv.x;
            sx[kq + 1][row] = xv.y;
            sx[kq + 2][row] = xv.z;
            sx[kq + 3][row] = xv.w;
        }
        // stage A: 16 k x 128 cols, thread -> (k, 8 cols)
        {
            const int k = tid >> 4;
            const int c = (tid & 15) * 8;
            const float* src = A + (size_t)(kc + k) * 256 + n0 + c;
            const float4 a0 = ((const float4*)src)[0];
            const float4 a1 = ((const float4*)src)[1];
            ((float4*)&swt[k][c])[0] = a0;
            ((float4*)&swt[k][c])[1] = a1;
        }
        __syncthreads();
        #pragma unroll
        for (int kk = 0; kk < KC; ++kk) {
            const float4 xv = *(const float4*)&sx[kk][r0];
            const float4 w0 = *(const float4*)&swt[kk][c0l];
            const float4 w1 = *(const float4*)&swt[kk][c0l + 4];
            const float xa[4] = {xv.x, xv.y, xv.z, xv.w};
            const float wb[8] = {w0.x, w0.y, w0.z, w0.w, w1.x, w1.y, w1.z, w1.w};
            #pragma unroll
            for (int i = 0; i < 4; ++i)
                #pragma unroll
                for (int j = 0; j < 8; ++j)
                    acc[i][j] = fmaf(xa[i], wb[j], acc[i][j]);
        }
        __syncthreads();
    }

    #pragma unroll
    for (int i = 0; i < 4; ++i) {
        float* dst = G + (size_t)(b0 + r0 + i) * 256 + n0 + c0l;
        ((float4*)dst)[0] = make_float4(acc[i][0], acc[i][1], acc[i][2], acc[i][3]);
        ((float4*)dst)[1] = make_float4(acc[i][4], acc[i][5], acc[i][6], acc[i][7]);
    }
}

// =====================================================================
// Kernel 4: per-row epilogue. One wave per row, 4 waves/block, grid 2048.
// attn = sigmoid(tanh(e+r)@Wa + ba); fused = attn*e+(1-attn)*r;
// ehr_p = relu(ehr@We+be); out = sigmoid(relu([fused,ehr_p])@Wf2 + bf2)
// =====================================================================
__global__ __launch_bounds__(256) void epilogue(
    const float* __restrict__ ehr, const float* __restrict__ ws,
    const float* __restrict__ Wa, const float* __restrict__ ba,
    const float* __restrict__ We, const float* __restrict__ be,
    const float* __restrict__ Wf2, const float* __restrict__ bf2,
    float* __restrict__ out)
{
    const int wid = threadIdx.x >> 6;
    const int lane = threadIdx.x & 63;
    const int row = blockIdx.x * 4 + wid;

    const float* ge = ws + OFF_GE + (size_t)row * 256;
    const float* gr = ws + OFF_GR + (size_t)row * 256;

    const float4 ev = *(const float4*)(ge + lane * 4);
    const float4 rv = *(const float4*)(gr + lane * 4);
    const float4 wav = *(const float4*)(Wa + lane * 4);

    float pa = tanhf_(ev.x + rv.x) * wav.x
             + tanhf_(ev.y + rv.y) * wav.y
             + tanhf_(ev.z + rv.z) * wav.z
             + tanhf_(ev.w + rv.w) * wav.w;
    #pragma unroll
    for (int m = 1; m < 64; m <<= 1) pa += __shfl_xor(pa, m, 64);
    const float at = sigmoidf_(pa + ba[0]);
    const float omat = 1.f - at;

    const float4 wfv = *(const float4*)(Wf2 + lane * 4);
    float po = fmaxf(at * ev.x + omat * rv.x, 0.f) * wfv.x
             + fmaxf(at * ev.y + omat * rv.y, 0.f) * wfv.y
             + fmaxf(at * ev.z + omat * rv.z, 0.f) * wfv.z
             + fmaxf(at * ev.w + omat * rv.w, 0.f) * wfv.w;

    // ehr branch: lane owns output feature e = lane
    const float x0 = ehr[(size_t)row * 64 + lane];
    float ep = be[lane];
    for (int d = 0; d < 64; ++d) {
        const float xd = __shfl(x0, d, 64);
        ep = fmaf(xd, We[d * 64 + lane], ep);
    }
    po += fmaxf(ep, 0.f) * Wf2[256 + lane];

    #pragma unroll
    for (int m = 1; m < 64; m <<= 1) po += __shfl_xor(po, m, 64);
    if (lane == 0) out[row] = sigmoidf_(po + bf2[0]);
}

// =====================================================================
extern "C" void kernel_launch(void* const* d_in, const int* in_sizes, int n_in,
                              void* d_out, int out_size, void* d_ws, size_t ws_size,
                              hipStream_t stream)
{
    (void)in_sizes; (void)n_in; (void)out_size; (void)ws_size;
    const float* ecc    = (const float*)d_in[0];
    const float* err    = (const float*)d_in[1];
    const float* ehr    = (const float*)d_in[2];
    const float* wt_ecc = (const float*)d_in[3];
    const float* bt_ecc = (const float*)d_in[4];
    const float* wt_err = (const float*)d_in[5];
    const float* bt_err = (const float*)d_in[6];
    const float* W0_ecc = (const float*)d_in[7];
    const float* W1_ecc = (const float*)d_in[8];
    const float* b_ecc  = (const float*)d_in[9];
    const float* W0_err = (const float*)d_in[10];
    const float* W1_err = (const float*)d_in[11];
    const float* b_err  = (const float*)d_in[12];
    const float* Wp_ecc = (const float*)d_in[13];
    const float* bp_ecc = (const float*)d_in[14];
    const float* Wp_err = (const float*)d_in[15];
    const float* bp_err = (const float*)d_in[16];
    const float* Wa     = (const float*)d_in[17];
    const float* ba     = (const float*)d_in[18];
    const float* We     = (const float*)d_in[19];
    const float* be     = (const float*)d_in[20];
    const float* Wf2    = (const float*)d_in[21];
    const float* bf2    = (const float*)d_in[22];
    float* ws  = (float*)d_ws;
    float* out = (float*)d_out;

    fold_temporal<<<dim3(102), dim3(256), 0, stream>>>(
        wt_ecc, bt_ecc, wt_err, bt_err, W0_ecc, W1_ecc, b_ecc, W0_err, W1_err, b_err, ws);
    fold_graph<<<dim3(KE + KRP + 2), dim3(256), 0, stream>>>(
        Wp_ecc, bp_ecc, Wp_err, bp_err, ws);
    gemm_g<<<dim3((B_TOT / 64) * 4), dim3(256), 0, stream>>>(ecc, err, ws);
    epilogue<<<dim3(B_TOT / 4), dim3(256), 0, stream>>>(
        ehr, ws, Wa, ba, We, be, Wf2, bf2, out);
}

// Round 3
// 155.564 us; speedup vs baseline: 2.1024x; 1.2996x over previous
//
#include <hip/hip_runtime.h>
#include <math.h>

// ---------------- problem constants ----------------
#define B_TOT 8192
#define KE 400      // 16 nodes * 25 t (ecc K)
#define KR 300      // 12 nodes * 25 t (err K)
#define MEP 416     // ecc K padded to 13*32
#define MRP 320     // err K padded to 10*32

// LDS strides (bf16 elements), padded for bank-conflict avoidance
#define SXE_LD 424
#define SXR_LD 328
#define SEH_LD 72
// epilogue LDS strides (floats)
#define GE_LD 260
#define EP_LD 68

// ---------------- workspace layout ----------------
// float offsets
#define OFF_WEFF0E 0
#define OFF_WEFF1E 1600
#define OFF_WEFF0R 3200
#define OFF_WEFF1R 4800
#define OFF_CVE    6400
#define OFF_CVR    6464
#define OFF_BE     6528
#define OFF_BR     6784
// ushort offsets (from d_ws base viewed as ushort*), 16B-aligned
#define U_AET 14080                   // AwT_ecc [256][416] bf16
#define U_ART (U_AET + 256 * MEP)     // AwT_err [256][320] bf16
#define U_WET (U_ART + 256 * MRP)     // WeT     [64][64]  bf16

typedef __attribute__((ext_vector_type(8))) short short8;
typedef __attribute__((ext_vector_type(4))) float floatx4;

__device__ __forceinline__ float sigmoidf_(float x) { return 1.f / (1.f + __expf(-x)); }
__device__ __forceinline__ float tanhf_(float x) { float e = __expf(2.f * x); return (e - 1.f) / (e + 1.f); }
__device__ __forceinline__ unsigned short f2bf(float x) {
    unsigned u = __float_as_uint(x);
    u += 0x7fffu + ((u >> 16) & 1u);          // round-to-nearest-even
    return (unsigned short)(u >> 16);
}

// =====================================================================
// Kernel 1: fold Conv1d into W0/W1 -> Weff [25][64] per (branch, order),
// cvec[64] = b + sum_ct bt[c]*(W0-W1)[ct]  (ring row-sum of L_hat = -1),
// and zero the bias accumulators (fold_graph atomicAdds into them).
// grid = 103 blocks x 256 threads
// =====================================================================
__global__ __launch_bounds__(256) void fold_temporal(
    const float* __restrict__ wt_ecc, const float* __restrict__ bt_ecc,
    const float* __restrict__ wt_err, const float* __restrict__ bt_err,
    const float* __restrict__ W0_ecc, const float* __restrict__ W1_ecc, const float* __restrict__ b_ecc,
    const float* __restrict__ W0_err, const float* __restrict__ W1_err, const float* __restrict__ b_err,
    float* __restrict__ ws)
{
    const int blk = blockIdx.x;
    const int tid = threadIdx.x;
    const int cq = tid >> 6;    // 0..3  (c-chunk of 8)
    const int g  = tid & 63;

    __shared__ float red[4][64];

    if (blk < 100) {
        const int m = blk / 25;       // 0: W0_ecc, 1: W1_ecc, 2: W0_err, 3: W1_err
        const int tin = blk % 25;
        const bool is_err = (m >= 2);
        const float* wt = is_err ? wt_err : wt_ecc;
        const float* W = (m & 1) ? (is_err ? W1_err : W1_ecc) : (is_err ? W0_err : W0_ecc);
        const int t0 = tin > 0 ? tin - 1 : 0;
        const int t1 = tin < 24 ? tin + 1 : 24;
        float s = 0.f;
        #pragma unroll
        for (int c8 = 0; c8 < 8; ++c8) {
            const int c = cq * 8 + c8;
            for (int t = t0; t <= t1; ++t) {
                const int k = tin - t + 1;           // 0..2
                s = fmaf(wt[c * 3 + k], W[(c * 25 + t) * 64 + g], s);
            }
        }
        red[cq][g] = s;
        __syncthreads();
        if (tid < 64)
            ws[m * 1600 + tin * 64 + g] = red[0][g] + red[1][g] + red[2][g] + red[3][g];
    } else if (blk < 102) {
        const bool is_err = (blk == 101);
        const float* bt = is_err ? bt_err : bt_ecc;
        const float* W0 = is_err ? W0_err : W0_ecc;
        const float* W1 = is_err ? W1_err : W1_ecc;
        const float* bb = is_err ? b_err : b_ecc;
        float s = 0.f;
        #pragma unroll
        for (int c8 = 0; c8 < 8; ++c8) {
            const int c = cq * 8 + c8;
            const float btc = bt[c];
            #pragma unroll
            for (int t = 0; t < 25; ++t) {
                const int ct = (c * 25 + t) * 64 + g;
                s = fmaf(btc, W0[ct] - W1[ct], s);
            }
        }
        red[cq][g] = s;
        __syncthreads();
        if (tid < 64)
            ws[(is_err ? OFF_CVR : OFF_CVE) + g] =
                bb[g] + red[0][g] + red[1][g] + red[2][g] + red[3][g];
    } else {
        // zero bias accumulators for fold_graph's atomicAdd
        ws[OFF_BE + tid] = 0.f;
        ws[OFF_BR + tid] = 0.f;
    }
}

// =====================================================================
// Kernel 2: fold Weff + ring stencil + Wp -> AwT (bf16, transposed, padded),
// biases (fp32, 16-way split + atomicAdd), WeT (bf16 transpose of We).
// grid = 416 + 320 + 16 + 16 + 1 = 769 blocks x 256 threads
// =====================================================================
__global__ __launch_bounds__(256) void fold_graph(
    const float* __restrict__ Wp_ecc, const float* __restrict__ bp_ecc,
    const float* __restrict__ Wp_err, const float* __restrict__ bp_err,
    const float* __restrict__ We,
    float* __restrict__ wsf, unsigned short* __restrict__ wsu)
{
    const int blk = blockIdx.x;
    const int h = threadIdx.x;

    if (blk < MEP) {
        const int k = blk;
        float s = 0.f;
        if (k < KE) {
            const int v = k / 25, tin = k % 25;
            const int vp = (v + 1) & 15, vm = (v + 15) & 15;
            const float* w0 = wsf + OFF_WEFF0E + tin * 64;
            const float* w1 = wsf + OFF_WEFF1E + tin * 64;
            #pragma unroll 4
            for (int g = 0; g < 64; ++g) {
                s = fmaf(w0[g], Wp_ecc[(v * 64 + g) * 256 + h], s);
                s = fmaf(-0.5f * w1[g], Wp_ecc[(vp * 64 + g) * 256 + h] + Wp_ecc[(vm * 64 + g) * 256 + h], s);
            }
        }
        wsu[U_AET + (size_t)h * MEP + k] = f2bf(s);
    } else if (blk < MEP + MRP) {
        const int k = blk - MEP;
        float s = 0.f;
        if (k < KR) {
            const int v = k / 25, tin = k % 25;
            const int vp = (v + 1) % 12, vm = (v + 11) % 12;
            const float* w0 = wsf + OFF_WEFF0R + tin * 64;
            const float* w1 = wsf + OFF_WEFF1R + tin * 64;
            #pragma unroll 4
            for (int g = 0; g < 64; ++g) {
                s = fmaf(w0[g], Wp_err[(v * 64 + g) * 256 + h], s);
                s = fmaf(-0.5f * w1[g], Wp_err[(vp * 64 + g) * 256 + h] + Wp_err[(vm * 64 + g) * 256 + h], s);
            }
        }
        wsu[U_ART + (size_t)h * MRP + k] = f2bf(s);
    } else if (blk < MEP + MRP + 16) {
        // bias_ecc: 1024 (v,g) terms split into 16 chunks of 64
        const int i = blk - (MEP + MRP);
        const float* cv = wsf + OFF_CVE;
        float s = (i == 0) ? bp_ecc[h] : 0.f;
        #pragma unroll 4
        for (int jj = 0; jj < 64; ++jj) {
            const int j = i * 64 + jj;
            s = fmaf(cv[j & 63], Wp_ecc[(size_t)j * 256 + h], s);
        }
        atomicAdd(&wsf[OFF_BE + h], s);
    } else if (blk < MEP + MRP + 32) {
        // bias_err: 768 terms, 12 active chunks
        const int i = blk - (MEP + MRP + 16);
        const float* cv = wsf + OFF_CVR;
        float s = (i == 0) ? bp_err[h] : 0.f;
        if (i < 12) {
            #pragma unroll 4
            for (int jj = 0; jj < 64; ++jj) {
                const int j = i * 64 + jj;
                s = fmaf(cv[j & 63], Wp_err[(size_t)j * 256 + h], s);
            }
        }
        atomicAdd(&wsf[OFF_BR + h], s);
    } else {
        // WeT[e][d] = We[d][e], bf16
        for (int it = 0; it < 16; ++it) {
            const int idx = it * 256 + h;
            const int e = idx >> 6, d = idx & 63;
            wsu[U_WET + e * 64 + d] = f2bf(We[d * 64 + e]);
        }
    }
}

// =====================================================================
// Kernel 3 (fused): per-block 32 batch rows.
//   - stage X_ecc/X_err/ehr fp32->bf16 into LDS
//   - MFMA 16x16x32 bf16: ecc_g, err_g (32x256 each), ehr_p (32x64)
//   - write C tiles to LDS, then in-block attention/fusion/final sigmoid
// grid = 256 blocks x 256 threads (4 waves)
// =====================================================================
__global__ __launch_bounds__(256) void fused_main(
    const float* __restrict__ ecc, const float* __restrict__ err, const float* __restrict__ ehr,
    const float* __restrict__ wsf, const unsigned short* __restrict__ wsu,
    const float* __restrict__ Wa, const float* __restrict__ ba,
    const float* __restrict__ be_, const float* __restrict__ Wf2, const float* __restrict__ bf2,
    float* __restrict__ out)
{
    const unsigned short* awt_e = wsu + U_AET;
    const unsigned short* awt_r = wsu + U_ART;
    const unsigned short* wet   = wsu + U_WET;
    const float* biasE = wsf + OFF_BE;
    const float* biasR = wsf + OFF_BR;

    // union: staging (52.7 KB) vs epilogue tiles (75.3 KB)
    __shared__ __align__(16) char smem[32 * GE_LD * 4 * 2 + 32 * EP_LD * 4];
    unsigned short* sxe = (unsigned short*)smem;          // [32][SXE_LD]
    unsigned short* sxr = sxe + 32 * SXE_LD;              // [32][SXR_LD]
    unsigned short* seh = sxr + 32 * SXR_LD;              // [32][SEH_LD]
    float* ge = (float*)smem;                             // [32][GE_LD]
    float* gr = ge + 32 * GE_LD;                          // [32][GE_LD]
    float* ep = gr + 32 * GE_LD;                          // [32][EP_LD]

    const int tid = threadIdx.x;
    const int row0 = blockIdx.x * 32;

    // ---- stage X_ecc: 32 rows x 106 quads (real quads < 100) ----
    for (int it = 0; it < 14; ++it) {
        const int f = it * 256 + tid;
        if (f < 32 * 106) {
            const int r = f / 106, q = f - r * 106;
            float4 v = make_float4(0.f, 0.f, 0.f, 0.f);
            if (q < 100) v = *(const float4*)(ecc + (size_t)(row0 + r) * KE + q * 4);
            const unsigned p0 = (unsigned)f2bf(v.x) | ((unsigned)f2bf(v.y) << 16);
            const unsigned p1 = (unsigned)f2bf(v.z) | ((unsigned)f2bf(v.w) << 16);
            *(uint2*)&sxe[r * SXE_LD + q * 4] = make_uint2(p0, p1);
        }
    }
    // ---- stage X_err: 32 rows x 82 quads (real quads < 75) ----
    for (int it = 0; it < 11; ++it) {
        const int f = it * 256 + tid;
        if (f < 32 * 82) {
            const int r = f / 82, q = f - r * 82;
            float4 v = make_float4(0.f, 0.f, 0.f, 0.f);
            if (q < 75) v = *(const float4*)(err + (size_t)(row0 + r) * KR + q * 4);
            const unsigned p0 = (unsigned)f2bf(v.x) | ((unsigned)f2bf(v.y) << 16);
            const unsigned p1 = (unsigned)f2bf(v.z) | ((unsigned)f2bf(v.w) << 16);
            *(uint2*)&sxr[r * SXR_LD + q * 4] = make_uint2(p0, p1);
        }
    }
    // ---- stage ehr: 32 rows x 16 quads exactly ----
    for (int it = 0; it < 2; ++it) {
        const int f = it * 256 + tid;
        const int r = f >> 4, q = f & 15;
        const float4 v = *(const float4*)(ehr + (size_t)(row0 + r) * 64 + q * 4);
        const unsigned p0 = (unsigned)f2bf(v.x) | ((unsigned)f2bf(v.y) << 16);
        const unsigned p1 = (unsigned)f2bf(v.z) | ((unsigned)f2bf(v.w) << 16);
        *(uint2*)&seh[r * SEH_LD + q * 4] = make_uint2(p0, p1);
    }
    __syncthreads();

    const int wv = tid >> 6, lane = tid & 63;
    const int lm = lane & 15, lq = lane >> 4;
    const int n0 = wv * 64;

    floatx4 accE[2][4], accR[2][4], accH[2];
    #pragma unroll
    for (int mt = 0; mt < 2; ++mt) {
        accH[mt] = (floatx4){0.f, 0.f, 0.f, 0.f};
        #pragma unroll
        for (int nt = 0; nt < 4; ++nt) {
            accE[mt][nt] = (floatx4){0.f, 0.f, 0.f, 0.f};
            accR[mt][nt] = (floatx4){0.f, 0.f, 0.f, 0.f};
        }
    }

    // ---- ehr_p = ehr @ We : wave handles N-tile wv (e = 16*wv + lm) ----
    #pragma unroll
    for (int kc = 0; kc < 2; ++kc) {
        const short8 b = *(const short8*)(wet + (wv * 16 + lm) * 64 + kc * 32 + lq * 8);
        #pragma unroll
        for (int mt = 0; mt < 2; ++mt) {
            const short8 a = *(const short8*)&seh[(mt * 16 + lm) * SEH_LD + kc * 32 + lq * 8];
            accH[mt] = __builtin_amdgcn_mfma_f32_16x16x32_bf16(a, b, accH[mt], 0, 0, 0);
        }
    }
    // ---- ecc branch: 13 k-chunks ----
    #pragma unroll
    for (int kc = 0; kc < 13; ++kc) {
        const short8 a0 = *(const short8*)&sxe[lm * SXE_LD + kc * 32 + lq * 8];
        const short8 a1 = *(const short8*)&sxe[(16 + lm) * SXE_LD + kc * 32 + lq * 8];
        #pragma unroll
        for (int nt = 0; nt < 4; ++nt) {
            const short8 b = *(const short8*)(awt_e + (size_t)(n0 + nt * 16 + lm) * MEP + kc * 32 + lq * 8);
            accE[0][nt] = __builtin_amdgcn_mfma_f32_16x16x32_bf16(a0, b, accE[0][nt], 0, 0, 0);
            accE[1][nt] = __builtin_amdgcn_mfma_f32_16x16x32_bf16(a1, b, accE[1][nt], 0, 0, 0);
        }
    }
    // ---- err branch: 10 k-chunks ----
    #pragma unroll
    for (int kc = 0; kc < 10; ++kc) {
        const short8 a0 = *(const short8*)&sxr[lm * SXR_LD + kc * 32 + lq * 8];
        const short8 a1 = *(const short8*)&sxr[(16 + lm) * SXR_LD + kc * 32 + lq * 8];
        #pragma unroll
        for (int nt = 0; nt < 4; ++nt) {
            const short8 b = *(const short8*)(awt_r + (size_t)(n0 + nt * 16 + lm) * MRP + kc * 32 + lq * 8);
            accR[0][nt] = __builtin_amdgcn_mfma_f32_16x16x32_bf16(a0, b, accR[0][nt], 0, 0, 0);
            accR[1][nt] = __builtin_amdgcn_mfma_f32_16x16x32_bf16(a1, b, accR[1][nt], 0, 0, 0);
        }
    }
    __syncthreads();   // all LDS staging reads done; reuse smem for C tiles

    // ---- spill C tiles to LDS (C layout: col=lane&15, row=lq*4+reg) ----
    #pragma unroll
    for (int mt = 0; mt < 2; ++mt) {
        #pragma unroll
        for (int nt = 0; nt < 4; ++nt) {
            #pragma unroll
            for (int rg = 0; rg < 4; ++rg) {
                const int rr = mt * 16 + lq * 4 + rg;
                const int cc = n0 + nt * 16 + lm;
                ge[rr * GE_LD + cc] = accE[mt][nt][rg];
                gr[rr * GE_LD + cc] = accR[mt][nt][rg];
            }
        }
        #pragma unroll
        for (int rg = 0; rg < 4; ++rg) {
            const int rr = mt * 16 + lq * 4 + rg;
            const int e = wv * 16 + lm;
            ep[rr * EP_LD + e] = fmaxf(accH[mt][rg] + be_[e], 0.f);
        }
    }
    __syncthreads();

    // ---- per-row epilogue: 8 threads per row (r = tid>>3, i = tid&7) ----
    const int r = tid >> 3, i = tid & 7;
    float pa = 0.f;
    #pragma unroll 4
    for (int j = 0; j < 32; ++j) {
        const int hh = j * 8 + i;
        const float ev = ge[r * GE_LD + hh] + biasE[hh];
        const float rv = gr[r * GE_LD + hh] + biasR[hh];
        pa += tanhf_(ev + rv) * Wa[hh];
    }
    pa += __shfl_xor(pa, 1, 64); pa += __shfl_xor(pa, 2, 64); pa += __shfl_xor(pa, 4, 64);
    const float at = sigmoidf_(pa + ba[0]);
    const float om = 1.f - at;

    float po = 0.f;
    #pragma unroll 4
    for (int j = 0; j < 32; ++j) {
        const int hh = j * 8 + i;
        const float ev = ge[r * GE_LD + hh] + biasE[hh];
        const float rv = gr[r * GE_LD + hh] + biasR[hh];
        po += fmaxf(at * ev + om * rv, 0.f) * Wf2[hh];
    }
    #pragma unroll
    for (int j = 0; j < 8; ++j) {
        const int e2 = j * 8 + i;
        po += ep[r * EP_LD + e2] * Wf2[256 + e2];   // ep already >= 0 (relu)
    }
    po += __shfl_xor(po, 1, 64); po += __shfl_xor(po, 2, 64); po += __shfl_xor(po, 4, 64);
    if (i == 0) out[row0 + r] = sigmoidf_(po + bf2[0]);
}

// =====================================================================
extern "C" void kernel_launch(void* const* d_in, const int* in_sizes, int n_in,
                              void* d_out, int out_size, void* d_ws, size_t ws_size,
                              hipStream_t stream)
{
    (void)in_sizes; (void)n_in; (void)out_size; (void)ws_size;
    const float* ecc    = (const float*)d_in[0];
    const float* err    = (const float*)d_in[1];
    const float* ehr    = (const float*)d_in[2];
    const float* wt_ecc = (const float*)d_in[3];
    const float* bt_ecc = (const float*)d_in[4];
    const float* wt_err = (const float*)d_in[5];
    const float* bt_err = (const float*)d_in[6];
    const float* W0_ecc = (const float*)d_in[7];
    const float* W1_ecc = (const float*)d_in[8];
    const float* b_ecc  = (const float*)d_in[9];
    const float* W0_err = (const float*)d_in[10];
    const float* W1_err = (const float*)d_in[11];
    const float* b_err  = (const float*)d_in[12];
    const float* Wp_ecc = (const float*)d_in[13];
    const float* bp_ecc = (const float*)d_in[14];
    const float* Wp_err = (const float*)d_in[15];
    const float* bp_err = (const float*)d_in[16];
    const float* Wa     = (const float*)d_in[17];
    const float* ba     = (const float*)d_in[18];
    const float* We     = (const float*)d_in[19];
    const float* be     = (const float*)d_in[20];
    const float* Wf2    = (const float*)d_in[21];
    const float* bf2    = (const float*)d_in[22];
    float* wsf = (float*)d_ws;
    unsigned short* wsu = (unsigned short*)d_ws;
    float* out = (float*)d_out;

    fold_temporal<<<dim3(103), dim3(256), 0, stream>>>(
        wt_ecc, bt_ecc, wt_err, bt_err, W0_ecc, W1_ecc, b_ecc, W0_err, W1_err, b_err, wsf);
    fold_graph<<<dim3(MEP + MRP + 32 + 1), dim3(256), 0, stream>>>(
        Wp_ecc, bp_ecc, Wp_err, bp_err, We, wsf, wsu);
    fused_main<<<dim3(B_TOT / 32), dim3(256), 0, stream>>>(
        ecc, err, ehr, wsf, wsu, Wa, ba, be, Wf2, bf2, out);
}

// Round 4
// 149.762 us; speedup vs baseline: 2.1838x; 1.0387x over previous
//
#include <hip/hip_runtime.h>
#include <math.h>

// ---------------- problem constants ----------------
#define B_TOT 8192
#define KE 400      // 16 nodes * 25 t (ecc K)
#define KR 300      // 12 nodes * 25 t (err K)
#define MEP 416     // ecc K padded to 13*32
#define MRP 320     // err K padded to 10*32

// LDS strides (bf16 elements), padded for bank-conflict avoidance
#define SXE_LD 424
#define SXR_LD 328
#define SEH_LD 72

// ---------------- workspace layout ----------------
// float offsets
#define OFF_WEFF0E 0
#define OFF_WEFF1E 1600
#define OFF_WEFF0R 3200
#define OFF_WEFF1R 4800
#define OFF_CVE    6400
#define OFF_CVR    6464
#define OFF_BE     6528
#define OFF_BR     6784
// ushort offsets (from d_ws base viewed as ushort*), 16B-aligned
#define U_AET 14080                   // AwT_ecc [256][416] bf16
#define U_ART (U_AET + 256 * MEP)     // AwT_err [256][320] bf16
#define U_WET (U_ART + 256 * MRP)     // WeT     [64][64]  bf16

typedef __attribute__((ext_vector_type(8))) short short8;
typedef __attribute__((ext_vector_type(4))) float floatx4;

__device__ __forceinline__ float sigmoidf_(float x) { return 1.f / (1.f + __expf(-x)); }
__device__ __forceinline__ float tanhf_(float x) { float e = __expf(2.f * x); return (e - 1.f) / (e + 1.f); }
__device__ __forceinline__ unsigned short f2bf(float x) {
    unsigned u = __float_as_uint(x);
    u += 0x7fffu + ((u >> 16) & 1u);          // round-to-nearest-even
    return (unsigned short)(u >> 16);
}

// =====================================================================
// Kernel 1: fold Conv1d into W0/W1 -> Weff [25][64] per (branch, order),
// cvec[64] = b + sum_ct bt[c]*(W0-W1)[ct]  (ring row-sum of L_hat = -1),
// and zero the bias accumulators (fold_graph atomicAdds into them).
// grid = 103 blocks x 256 threads
// =====================================================================
__global__ __launch_bounds__(256) void fold_temporal(
    const float* __restrict__ wt_ecc, const float* __restrict__ bt_ecc,
    const float* __restrict__ wt_err, const float* __restrict__ bt_err,
    const float* __restrict__ W0_ecc, const float* __restrict__ W1_ecc, const float* __restrict__ b_ecc,
    const float* __restrict__ W0_err, const float* __restrict__ W1_err, const float* __restrict__ b_err,
    float* __restrict__ ws)
{
    const int blk = blockIdx.x;
    const int tid = threadIdx.x;
    const int cq = tid >> 6;    // 0..3  (c-chunk of 8)
    const int g  = tid & 63;

    __shared__ float red[4][64];

    if (blk < 100) {
        const int m = blk / 25;       // 0: W0_ecc, 1: W1_ecc, 2: W0_err, 3: W1_err
        const int tin = blk % 25;
        const bool is_err = (m >= 2);
        const float* wt = is_err ? wt_err : wt_ecc;
        const float* W = (m & 1) ? (is_err ? W1_err : W1_ecc) : (is_err ? W0_err : W0_ecc);
        const int t0 = tin > 0 ? tin - 1 : 0;
        const int t1 = tin < 24 ? tin + 1 : 24;
        float s = 0.f;
        #pragma unroll
        for (int c8 = 0; c8 < 8; ++c8) {
            const int c = cq * 8 + c8;
            for (int t = t0; t <= t1; ++t) {
                const int k = tin - t + 1;           // 0..2
                s = fmaf(wt[c * 3 + k], W[(c * 25 + t) * 64 + g], s);
            }
        }
        red[cq][g] = s;
        __syncthreads();
        if (tid < 64)
            ws[m * 1600 + tin * 64 + g] = red[0][g] + red[1][g] + red[2][g] + red[3][g];
    } else if (blk < 102) {
        const bool is_err = (blk == 101);
        const float* bt = is_err ? bt_err : bt_ecc;
        const float* W0 = is_err ? W0_err : W0_ecc;
        const float* W1 = is_err ? W1_err : W1_ecc;
        const float* bb = is_err ? b_err : b_ecc;
        float s = 0.f;
        #pragma unroll
        for (int c8 = 0; c8 < 8; ++c8) {
            const int c = cq * 8 + c8;
            const float btc = bt[c];
            #pragma unroll
            for (int t = 0; t < 25; ++t) {
                const int ct = (c * 25 + t) * 64 + g;
                s = fmaf(btc, W0[ct] - W1[ct], s);
            }
        }
        red[cq][g] = s;
        __syncthreads();
        if (tid < 64)
            ws[(is_err ? OFF_CVR : OFF_CVE) + g] =
                bb[g] + red[0][g] + red[1][g] + red[2][g] + red[3][g];
    } else {
        // zero bias accumulators for fold_graph's atomicAdd
        ws[OFF_BE + tid] = 0.f;
        ws[OFF_BR + tid] = 0.f;
    }
}

// =====================================================================
// Kernel 2: fold Weff + ring stencil + Wp -> AwT (bf16, transposed, padded),
// biases (fp32, 16-way split + atomicAdd), WeT (bf16 transpose of We).
// grid = 416 + 320 + 16 + 16 + 1 = 769 blocks x 256 threads
// =====================================================================
__global__ __launch_bounds__(256) void fold_graph(
    const float* __restrict__ Wp_ecc, const float* __restrict__ bp_ecc,
    const float* __restrict__ Wp_err, const float* __restrict__ bp_err,
    const float* __restrict__ We,
    float* __restrict__ wsf, unsigned short* __restrict__ wsu)
{
    const int blk = blockIdx.x;
    const int h = threadIdx.x;

    if (blk < MEP) {
        const int k = blk;
        float s = 0.f;
        if (k < KE) {
            const int v = k / 25, tin = k % 25;
            const int vp = (v + 1) & 15, vm = (v + 15) & 15;
            const float* w0 = wsf + OFF_WEFF0E + tin * 64;
            const float* w1 = wsf + OFF_WEFF1E + tin * 64;
            #pragma unroll 4
            for (int g = 0; g < 64; ++g) {
                s = fmaf(w0[g], Wp_ecc[(v * 64 + g) * 256 + h], s);
                s = fmaf(-0.5f * w1[g], Wp_ecc[(vp * 64 + g) * 256 + h] + Wp_ecc[(vm * 64 + g) * 256 + h], s);
            }
        }
        wsu[U_AET + (size_t)h * MEP + k] = f2bf(s);
    } else if (blk < MEP + MRP) {
        const int k = blk - MEP;
        float s = 0.f;
        if (k < KR) {
            const int v = k / 25, tin = k % 25;
            const int vp = (v + 1) % 12, vm = (v + 11) % 12;
            const float* w0 = wsf + OFF_WEFF0R + tin * 64;
            const float* w1 = wsf + OFF_WEFF1R + tin * 64;
            #pragma unroll 4
            for (int g = 0; g < 64; ++g) {
                s = fmaf(w0[g], Wp_err[(v * 64 + g) * 256 + h], s);
                s = fmaf(-0.5f * w1[g], Wp_err[(vp * 64 + g) * 256 + h] + Wp_err[(vm * 64 + g) * 256 + h], s);
            }
        }
        wsu[U_ART + (size_t)h * MRP + k] = f2bf(s);
    } else if (blk < MEP + MRP + 16) {
        // bias_ecc: 1024 (v,g) terms split into 16 chunks of 64
        const int i = blk - (MEP + MRP);
        const float* cv = wsf + OFF_CVE;
        float s = (i == 0) ? bp_ecc[h] : 0.f;
        #pragma unroll 4
        for (int jj = 0; jj < 64; ++jj) {
            const int j = i * 64 + jj;
            s = fmaf(cv[j & 63], Wp_ecc[(size_t)j * 256 + h], s);
        }
        atomicAdd(&wsf[OFF_BE + h], s);
    } else if (blk < MEP + MRP + 32) {
        // bias_err: 768 terms, 12 active chunks
        const int i = blk - (MEP + MRP + 16);
        const float* cv = wsf + OFF_CVR;
        float s = (i == 0) ? bp_err[h] : 0.f;
        if (i < 12) {
            #pragma unroll 4
            for (int jj = 0; jj < 64; ++jj) {
                const int j = i * 64 + jj;
                s = fmaf(cv[j & 63], Wp_err[(size_t)j * 256 + h], s);
            }
        }
        atomicAdd(&wsf[OFF_BR + h], s);
    } else {
        // WeT[e][d] = We[d][e], bf16
        for (int it = 0; it < 16; ++it) {
            const int idx = it * 256 + h;
            const int e = idx >> 6, d = idx & 63;
            wsu[U_WET + e * 64 + d] = f2bf(We[d * 64 + e]);
        }
    }
}

// =====================================================================
// Kernel 3 (fused): per-block 32 batch rows, 4 waves.
//   - stage X_ecc/X_err/ehr fp32->bf16 into LDS (51.5 KB -> 3 blocks/CU)
//   - MFMA 16x16x32 bf16: ecc_g, err_g (32x256), ehr_p (32x64)
//   - epilogue entirely in registers + shfl; only 288 floats of partials in LDS
// grid = 256 blocks x 256 threads
// =====================================================================
__global__ __launch_bounds__(256, 3) void fused_main(
    const float* __restrict__ ecc, const float* __restrict__ err, const float* __restrict__ ehr,
    const float* __restrict__ wsf, const unsigned short* __restrict__ wsu,
    const float* __restrict__ Wa, const float* __restrict__ ba,
    const float* __restrict__ be_, const float* __restrict__ Wf2, const float* __restrict__ bf2,
    float* __restrict__ out)
{
    const unsigned short* awt_e = wsu + U_AET;
    const unsigned short* awt_r = wsu + U_ART;
    const unsigned short* wet   = wsu + U_WET;
    const float* biasE = wsf + OFF_BE;
    const float* biasR = wsf + OFF_BR;

    __shared__ __align__(16) char smem[32 * SXE_LD * 2 + 32 * SXR_LD * 2 + 32 * SEH_LD * 2];
    unsigned short* sxe = (unsigned short*)smem;          // [32][SXE_LD]
    unsigned short* sxr = sxe + 32 * SXE_LD;              // [32][SXR_LD]
    unsigned short* seh = sxr + 32 * SXR_LD;              // [32][SEH_LD]
    // epilogue scratch overlays sxe (used only after the post-MFMA barrier)
    float* pa_part = (float*)smem;                        // [4][32]
    float* at_arr  = pa_part + 128;                       // [32]
    float* po_part = at_arr + 32;                         // [4][32]

    const int tid = threadIdx.x;
    const int row0 = blockIdx.x * 32;

    // ---- stage X_ecc: 32 rows x 106 quads (real quads < 100) ----
    for (int it = 0; it < 14; ++it) {
        const int f = it * 256 + tid;
        if (f < 32 * 106) {
            const int r = f / 106, q = f - r * 106;
            float4 v = make_float4(0.f, 0.f, 0.f, 0.f);
            if (q < 100) v = *(const float4*)(ecc + (size_t)(row0 + r) * KE + q * 4);
            const unsigned p0 = (unsigned)f2bf(v.x) | ((unsigned)f2bf(v.y) << 16);
            const unsigned p1 = (unsigned)f2bf(v.z) | ((unsigned)f2bf(v.w) << 16);
            *(uint2*)&sxe[r * SXE_LD + q * 4] = make_uint2(p0, p1);
        }
    }
    // ---- stage X_err: 32 rows x 82 quads (real quads < 75) ----
    for (int it = 0; it < 11; ++it) {
        const int f = it * 256 + tid;
        if (f < 32 * 82) {
            const int r = f / 82, q = f - r * 82;
            float4 v = make_float4(0.f, 0.f, 0.f, 0.f);
            if (q < 75) v = *(const float4*)(err + (size_t)(row0 + r) * KR + q * 4);
            const unsigned p0 = (unsigned)f2bf(v.x) | ((unsigned)f2bf(v.y) << 16);
            const unsigned p1 = (unsigned)f2bf(v.z) | ((unsigned)f2bf(v.w) << 16);
            *(uint2*)&sxr[r * SXR_LD + q * 4] = make_uint2(p0, p1);
        }
    }
    // ---- stage ehr: 32 rows x 16 quads exactly ----
    for (int it = 0; it < 2; ++it) {
        const int f = it * 256 + tid;
        const int r = f >> 4, q = f & 15;
        const float4 v = *(const float4*)(ehr + (size_t)(row0 + r) * 64 + q * 4);
        const unsigned p0 = (unsigned)f2bf(v.x) | ((unsigned)f2bf(v.y) << 16);
        const unsigned p1 = (unsigned)f2bf(v.z) | ((unsigned)f2bf(v.w) << 16);
        *(uint2*)&seh[r * SEH_LD + q * 4] = make_uint2(p0, p1);
    }
    __syncthreads();

    const int wv = tid >> 6, lane = tid & 63;
    const int lm = lane & 15, lq = lane >> 4;
    const int n0 = wv * 64;

    floatx4 accE[2][4], accR[2][4], accH[2];
    #pragma unroll
    for (int mt = 0; mt < 2; ++mt) {
        accH[mt] = (floatx4){0.f, 0.f, 0.f, 0.f};
        #pragma unroll
        for (int nt = 0; nt < 4; ++nt) {
            accE[mt][nt] = (floatx4){0.f, 0.f, 0.f, 0.f};
            accR[mt][nt] = (floatx4){0.f, 0.f, 0.f, 0.f};
        }
    }

    // ---- ehr_p = ehr @ We : wave handles e-slab wv (e = 16*wv + lm) ----
    #pragma unroll
    for (int kc = 0; kc < 2; ++kc) {
        const short8 b = *(const short8*)(wet + (wv * 16 + lm) * 64 + kc * 32 + lq * 8);
        #pragma unroll
        for (int mt = 0; mt < 2; ++mt) {
            const short8 a = *(const short8*)&seh[(mt * 16 + lm) * SEH_LD + kc * 32 + lq * 8];
            accH[mt] = __builtin_amdgcn_mfma_f32_16x16x32_bf16(a, b, accH[mt], 0, 0, 0);
        }
    }
    // ---- ecc branch: 13 k-chunks ----
    #pragma unroll
    for (int kc = 0; kc < 13; ++kc) {
        const short8 a0 = *(const short8*)&sxe[lm * SXE_LD + kc * 32 + lq * 8];
        const short8 a1 = *(const short8*)&sxe[(16 + lm) * SXE_LD + kc * 32 + lq * 8];
        #pragma unroll
        for (int nt = 0; nt < 4; ++nt) {
            const short8 b = *(const short8*)(awt_e + (size_t)(n0 + nt * 16 + lm) * MEP + kc * 32 + lq * 8);
            accE[0][nt] = __builtin_amdgcn_mfma_f32_16x16x32_bf16(a0, b, accE[0][nt], 0, 0, 0);
            accE[1][nt] = __builtin_amdgcn_mfma_f32_16x16x32_bf16(a1, b, accE[1][nt], 0, 0, 0);
        }
    }
    // ---- err branch: 10 k-chunks ----
    #pragma unroll
    for (int kc = 0; kc < 10; ++kc) {
        const short8 a0 = *(const short8*)&sxr[lm * SXR_LD + kc * 32 + lq * 8];
        const short8 a1 = *(const short8*)&sxr[(16 + lm) * SXR_LD + kc * 32 + lq * 8];
        #pragma unroll
        for (int nt = 0; nt < 4; ++nt) {
            const short8 b = *(const short8*)(awt_r + (size_t)(n0 + nt * 16 + lm) * MRP + kc * 32 + lq * 8);
            accR[0][nt] = __builtin_amdgcn_mfma_f32_16x16x32_bf16(a0, b, accR[0][nt], 0, 0, 0);
            accR[1][nt] = __builtin_amdgcn_mfma_f32_16x16x32_bf16(a1, b, accR[1][nt], 0, 0, 0);
        }
    }

    // ---- per-lane epilogue constants (L2-hot scalar loads) ----
    float bE[4], bR[4], wa[4], wf[4];
    #pragma unroll
    for (int nt = 0; nt < 4; ++nt) {
        const int h = n0 + nt * 16 + lm;
        bE[nt] = biasE[h]; bR[nt] = biasR[h]; wa[nt] = Wa[h]; wf[nt] = Wf2[h];
    }
    const int e_lane = wv * 16 + lm;
    const float eh_be = be_[e_lane];
    const float eh_wf = Wf2[256 + e_lane];

    // ---- pass 1: attention logits, pure register + shfl ----
    float pa_lane[2][4];
    #pragma unroll
    for (int mt = 0; mt < 2; ++mt)
        #pragma unroll
        for (int rg = 0; rg < 4; ++rg) {
            float s = 0.f;
            #pragma unroll
            for (int nt = 0; nt < 4; ++nt) {
                const float ev = accE[mt][nt][rg] + bE[nt];
                const float rv = accR[mt][nt][rg] + bR[nt];
                s = fmaf(tanhf_(ev + rv), wa[nt], s);
            }
            s += __shfl_xor(s, 1, 64); s += __shfl_xor(s, 2, 64);
            s += __shfl_xor(s, 4, 64); s += __shfl_xor(s, 8, 64);
            pa_lane[mt][rg] = s;
        }

    __syncthreads();   // all staging-LDS reads complete; safe to overlay scratch
    if (lm == 0) {
        #pragma unroll
        for (int mt = 0; mt < 2; ++mt)
            #pragma unroll
            for (int rg = 0; rg < 4; ++rg)
                pa_part[wv * 32 + mt * 16 + lq * 4 + rg] = pa_lane[mt][rg];
    }
    __syncthreads();
    if (tid < 32)
        at_arr[tid] = sigmoidf_(pa_part[tid] + pa_part[32 + tid] + pa_part[64 + tid] + pa_part[96 + tid] + ba[0]);
    __syncthreads();

    // ---- pass 2: fused + EHR dot with Wf2, register + shfl ----
    float po_lane[2][4];
    #pragma unroll
    for (int mt = 0; mt < 2; ++mt)
        #pragma unroll
        for (int rg = 0; rg < 4; ++rg) {
            const int r = mt * 16 + lq * 4 + rg;
            const float at = at_arr[r];
            const float om = 1.f - at;
            float s = 0.f;
            #pragma unroll
            for (int nt = 0; nt < 4; ++nt) {
                const float ev = accE[mt][nt][rg] + bE[nt];
                const float rv = accR[mt][nt][rg] + bR[nt];
                s = fmaf(fmaxf(at * ev + om * rv, 0.f), wf[nt], s);
            }
            s = fmaf(fmaxf(accH[mt][rg] + eh_be, 0.f), eh_wf, s);
            s += __shfl_xor(s, 1, 64); s += __shfl_xor(s, 2, 64);
            s += __shfl_xor(s, 4, 64); s += __shfl_xor(s, 8, 64);
            po_lane[mt][rg] = s;
        }
    if (lm == 0) {
        #pragma unroll
        for (int mt = 0; mt < 2; ++mt)
            #pragma unroll
            for (int rg = 0; rg < 4; ++rg)
                po_part[wv * 32 + mt * 16 + lq * 4 + rg] = po_lane[mt][rg];
    }
    __syncthreads();
    if (tid < 32)
        out[row0 + tid] = sigmoidf_(po_part[tid] + po_part[32 + tid] + po_part[64 + tid] + po_part[96 + tid] + bf2[0]);
}

// =====================================================================
extern "C" void kernel_launch(void* const* d_in, const int* in_sizes, int n_in,
                              void* d_out, int out_size, void* d_ws, size_t ws_size,
                              hipStream_t stream)
{
    (void)in_sizes; (void)n_in; (void)out_size; (void)ws_size;
    const float* ecc    = (const float*)d_in[0];
    const float* err    = (const float*)d_in[1];
    const float* ehr    = (const float*)d_in[2];
    const float* wt_ecc = (const float*)d_in[3];
    const float* bt_ecc = (const float*)d_in[4];
    const float* wt_err = (const float*)d_in[5];
    const float* bt_err = (const float*)d_in[6];
    const float* W0_ecc = (const float*)d_in[7];
    const float* W1_ecc = (const float*)d_in[8];
    const float* b_ecc  = (const float*)d_in[9];
    const float* W0_err = (const float*)d_in[10];
    const float* W1_err = (const float*)d_in[11];
    const float* b_err  = (const float*)d_in[12];
    const float* Wp_ecc = (const float*)d_in[13];
    const float* bp_ecc = (const float*)d_in[14];
    const float* Wp_err = (const float*)d_in[15];
    const float* bp_err = (const float*)d_in[16];
    const float* Wa     = (const float*)d_in[17];
    const float* ba     = (const float*)d_in[18];
    const float* We     = (const float*)d_in[19];
    const float* be     = (const float*)d_in[20];
    const float* Wf2    = (const float*)d_in[21];
    const float* bf2    = (const float*)d_in[22];
    float* wsf = (float*)d_ws;
    unsigned short* wsu = (unsigned short*)d_ws;
    float* out = (float*)d_out;

    fold_temporal<<<dim3(103), dim3(256), 0, stream>>>(
        wt_ecc, bt_ecc, wt_err, bt_err, W0_ecc, W1_ecc, b_ecc, W0_err, W1_err, b_err, wsf);
    fold_graph<<<dim3(MEP + MRP + 32 + 1), dim3(256), 0, stream>>>(
        Wp_ecc, bp_ecc, Wp_err, bp_err, We, wsf, wsu);
    fused_main<<<dim3(B_TOT / 32), dim3(256), 0, stream>>>(
        ecc, err, ehr, wsf, wsu, Wa, ba, be, Wf2, bf2, out);
}